// Round 6
// baseline (846.065 us; speedup 1.0000x reference)
//
#include <hip/hip_runtime.h>
#include <stdint.h>
#include <math.h>

// ---------------------------------------------------------------------------
// Model_14104672600612 — fp32 graph-attention pipeline on MI355X (gfx950)
// R6: (1) k_attn1 grid 512->1024 (c split 4-way) -> 3 blocks/CU (R5: grid-
//     capped at 2, VALUBusy 74%). (2) k_gemm1 split-K=2 (804 blocks, dynamic
//     balance; fused partial-sum in k_pool; ws_size-guarded fallback) +
//     register prefetch of the HBM-streamed A tile. (3) k_head stages h in
//     LDS (was 128 uncoalesced global scalar loads/thread).
// fp32 throughout (no fp32 MFMA on CDNA4; keeps top-k node ranking stable).
// ---------------------------------------------------------------------------

#define BS 256
#define SEQ 201
#define DS 1024
#define D1 128
#define D2 64
#define NN 67
#define NP 53
#define ROWS1 (BS * SEQ)   // 51456
#define ROWS2 (BS * NN)    // 17152

#define SELU_LAM 1.0507009873554805f
#define SELU_ALP 1.6732632423543772f

__device__ __forceinline__ float selu_f(float x) {
    return (x > 0.0f) ? SELU_LAM * x : SELU_LAM * (SELU_ALP * expm1f(x));
}

__device__ __forceinline__ float fc(float4 v, int k) {
    switch (k & 3) {
        case 0: return v.x;
        case 1: return v.y;
        case 2: return v.z;
        default: return v.w;
    }
}

// ---------------------------------------------------------------------------
// k_pre: WllT[c][k] = Wll[k][c] (128x1024), WapT[c][d] = Wap[d][c] (64x128),
// r1/r2 = 1/sqrt(var+eps).
// ---------------------------------------------------------------------------
__global__ __launch_bounds__(256) void k_pre(
    const float* __restrict__ Wll, const float* __restrict__ Wap,
    const float* __restrict__ v1, const float* __restrict__ v2,
    float* __restrict__ WllT, float* __restrict__ WapT,
    float* __restrict__ r1, float* __restrict__ r2)
{
    int t = blockIdx.x * 256 + threadIdx.x;
    if (t < 131072) {
        int c = t >> 10, k = t & 1023;
        WllT[t] = Wll[k * D1 + c];
    } else if (t < 139264) {
        int i = t - 131072; int c = i >> 7, d = i & 127;
        WapT[i] = Wap[d * D2 + c];
    } else if (t < 139392) {
        int d = t - 139264;
        r1[d] = 1.0f / sqrtf(v1[d] + 1e-5f);
    } else if (t < 139456) {
        int c = t - 139392;
        r2[c] = 1.0f / sqrtf(v2[c] + 1e-5f);
    }
}

// ---------------------------------------------------------------------------
// k_gemm1 (R6): y = feat @ Wll, 128x128 tile, BK=32, 8x8 micro-tile.
// nsplit==2: grid 804, block = (tile, k-half), K=512 each, out y0/y1.
// nsplit==1: grid 402, K=1024, out y0. A-tile register-prefetched (HBM);
// B read per-iteration (L2-hot WllT).
// ---------------------------------------------------------------------------
__global__ __launch_bounds__(256) void k_gemm1(
    const float* __restrict__ A, const float* __restrict__ Bt,
    float* __restrict__ y0, float* __restrict__ y1, int nsplit)
{
    __shared__ __align__(16) float As[128 * 36];
    __shared__ __align__(16) float Bs[128 * 36];
    int tid = threadIdx.x;
    int bx = blockIdx.x;
    int tile, kb, nk;
    float* yout;
    if (nsplit == 2) {
        tile = bx >> 1; int half = bx & 1;
        kb = half << 9; nk = 512;
        yout = half ? y1 : y0;
    } else {
        tile = bx; kb = 0; nk = 1024; yout = y0;
    }
    int row0 = tile * 128;
    int ty = tid >> 4, tx = tid & 15;
    float acc[8][8];
#pragma unroll
    for (int r = 0; r < 8; ++r)
#pragma unroll
        for (int m = 0; m < 8; ++m) acc[r][m] = 0.0f;

    int lr = tid >> 1, lc = (tid & 1) * 16;
    const float* gA = A + (size_t)(row0 + lr) * DS + kb + lc;
    const float* gB = Bt + (size_t)lr * DS + kb + lc;
    float* wa = As + lr * 36 + lc;
    float* wb = Bs + lr * 36 + lc;

    float4 pa0 = *(const float4*)(gA);
    float4 pa1 = *(const float4*)(gA + 4);
    float4 pa2 = *(const float4*)(gA + 8);
    float4 pa3 = *(const float4*)(gA + 12);

    for (int k0 = 0; k0 < nk; k0 += 32) {
        float4 b0 = *(const float4*)(gB + k0);
        float4 b1 = *(const float4*)(gB + k0 + 4);
        float4 b2 = *(const float4*)(gB + k0 + 8);
        float4 b3 = *(const float4*)(gB + k0 + 12);
        __syncthreads();
        *(float4*)(wa)      = pa0; *(float4*)(wa + 4)  = pa1;
        *(float4*)(wa + 8)  = pa2; *(float4*)(wa + 12) = pa3;
        *(float4*)(wb)      = b0;  *(float4*)(wb + 4)  = b1;
        *(float4*)(wb + 8)  = b2;  *(float4*)(wb + 12) = b3;
        __syncthreads();
        if (k0 + 32 < nk) {                      // prefetch next A tile (HBM)
            pa0 = *(const float4*)(gA + k0 + 32);
            pa1 = *(const float4*)(gA + k0 + 36);
            pa2 = *(const float4*)(gA + k0 + 40);
            pa3 = *(const float4*)(gA + k0 + 44);
        }
#pragma unroll
        for (int k4 = 0; k4 < 8; ++k4) {
            float4 av[8], bv[8];
#pragma unroll
            for (int r = 0; r < 8; ++r)
                av[r] = *(const float4*)(As + (ty + 16 * r) * 36 + k4 * 4);
#pragma unroll
            for (int m = 0; m < 8; ++m)
                bv[m] = *(const float4*)(Bs + (tx + 16 * m) * 36 + k4 * 4);
#pragma unroll
            for (int r = 0; r < 8; ++r)
#pragma unroll
                for (int m = 0; m < 8; ++m) {
                    acc[r][m] += av[r].x * bv[m].x;
                    acc[r][m] += av[r].y * bv[m].y;
                    acc[r][m] += av[r].z * bv[m].z;
                    acc[r][m] += av[r].w * bv[m].w;
                }
        }
    }
#pragma unroll
    for (int r = 0; r < 8; ++r)
#pragma unroll
        for (int m = 0; m < 8; ++m)
            yout[(size_t)(row0 + ty + 16 * r) * D1 + tx + 16 * m] = acc[r][m];
}

// ---------------------------------------------------------------------------
// k_pool: (+partial sum), +b_ll, maxpool3, BN1, SELU -> X (17152x128)
// ---------------------------------------------------------------------------
__global__ __launch_bounds__(256) void k_pool(
    const float* __restrict__ y0, const float* __restrict__ y1, int dual,
    const float* __restrict__ bll,
    const float* __restrict__ g1, const float* __restrict__ b1,
    const float* __restrict__ m1, const float* __restrict__ r1,
    float* __restrict__ X)
{
    int t = blockIdx.x * 256 + threadIdx.x;
    int d = t & 127, rem = t >> 7;
    int n = rem % NN, b = rem / NN;
    size_t base = ((size_t)(b * SEQ + 3 * n)) * D1 + d;
    float bl = bll[d];
    float s0 = y0[base], s1 = y0[base + D1], s2 = y0[base + 2 * D1];
    if (dual) {
        s0 += y1[base]; s1 += y1[base + D1]; s2 += y1[base + 2 * D1];
    }
    float v = fmaxf(fmaxf(s0 + bl, s1 + bl), s2 + bl);
    v = (v - m1[d]) * r1[d] * g1[d] + b1[d];
    X[(size_t)rem * D1 + d] = selu_f(v);
}

// ---------------------------------------------------------------------------
// k_attn1 (R6): 1024 blocks = (batch b = blk>>2, c-quarter z = blk&3).
// LDS: Xs[80x132] only (42.2 KB -> 3 blocks/CU). Thread (ti,tj) owns
// supercells a<=m; accumulates eacc over cg in [4z, 4z+4); writes symmetric
// partial tile to epart[blk][80][80].
// ---------------------------------------------------------------------------
__global__ __launch_bounds__(256) void k_attn1(
    const float* __restrict__ X, const float* __restrict__ WapT,
    const float* __restrict__ bap, const float* __restrict__ attw,
    float* __restrict__ epart)
{
    __shared__ __align__(16) float Xs[80 * 132];   // 42.2 KB
    int tid = threadIdx.x;
    int blk = blockIdx.x;
    int b = blk >> 2, z = blk & 3;
    const float* Xb = X + (size_t)b * NN * D1;

#pragma unroll
    for (int q = 0; q < 40; ++q) {
        int t = q * 256 + tid;
        int r = t >> 7, d = t & 127;
        Xs[r * 132 + d] = (r < NN) ? Xb[(size_t)r * D1 + d] : 0.0f;
    }
    __syncthreads();

    int ti = tid >> 4, tj = tid & 15;

    float eacc[5][5];
#pragma unroll
    for (int a = 0; a < 5; ++a)
#pragma unroll
        for (int m = a; m < 5; ++m) eacc[a][m] = 0.0f;

    for (int cg = z * 4; cg < z * 4 + 4; ++cg) {
        float E[5][5][4];
#pragma unroll
        for (int a = 0; a < 5; ++a)
#pragma unroll
            for (int m = a; m < 5; ++m)
#pragma unroll
                for (int c = 0; c < 4; ++c) E[a][m][c] = 0.0f;

#pragma unroll 2
        for (int k4 = 0; k4 < 32; ++k4) {
            float4 xa[5], xv[5], w[4];
#pragma unroll
            for (int a = 0; a < 5; ++a)
                xa[a] = *(const float4*)(Xs + (ti + 16 * a) * 132 + k4 * 4);
#pragma unroll
            for (int m = 0; m < 5; ++m)
                xv[m] = *(const float4*)(Xs + (tj + 16 * m) * 132 + k4 * 4);
#pragma unroll
            for (int c = 0; c < 4; ++c)
                w[c] = *(const float4*)(WapT + (cg * 4 + c) * D1 + k4 * 4);
#pragma unroll
            for (int kk = 0; kk < 4; ++kk) {
#pragma unroll
                for (int a = 0; a < 5; ++a) {
                    float pa = fc(xa[a], kk);
#pragma unroll
                    for (int m = a; m < 5; ++m) {
                        float P = pa * fc(xv[m], kk);
                        E[a][m][0] += P * fc(w[0], kk);
                        E[a][m][1] += P * fc(w[1], kk);
                        E[a][m][2] += P * fc(w[2], kk);
                        E[a][m][3] += P * fc(w[3], kk);
                    }
                }
            }
        }
#pragma unroll
        for (int c = 0; c < 4; ++c) {
            float bc = bap[cg * 4 + c], ac = attw[cg * 4 + c];
#pragma unroll
            for (int a = 0; a < 5; ++a)
#pragma unroll
                for (int m = a; m < 5; ++m)
                    eacc[a][m] += tanhf(E[a][m][c] + bc) * ac;
        }
    }

    float* ep = epart + (size_t)blk * 6400;
#pragma unroll
    for (int a = 0; a < 5; ++a)
#pragma unroll
        for (int m = a; m < 5; ++m) {
            int i = ti + 16 * a, j = tj + 16 * m;
            ep[i * 80 + j] = eacc[a][m];
            if (a < m) ep[j * 80 + i] = eacc[a][m];
        }
}

// ---------------------------------------------------------------------------
// k_attn2 (R6): 256 blocks (one per batch). Sum the four c-quarter partials,
// softmax over j, then xa = att @ X -> XA.
// ---------------------------------------------------------------------------
__global__ __launch_bounds__(256) void k_attn2(
    const float* __restrict__ X, const float* __restrict__ epart,
    float* __restrict__ XA)
{
    __shared__ __align__(16) float Xs[80 * 132];   // 42.2 KB
    __shared__ float e[80 * 85];                   // 27.2 KB
    int tid = threadIdx.x;
    int b = blockIdx.x;
    const float* Xb = X + (size_t)b * NN * D1;

#pragma unroll
    for (int q = 0; q < 40; ++q) {
        int t = q * 256 + tid;
        int r = t >> 7, d = t & 127;
        Xs[r * 132 + d] = (r < NN) ? Xb[(size_t)r * D1 + d] : 0.0f;
    }
    const float* e0 = epart + (size_t)(b * 4) * 6400;
    for (int t = tid; t < 6400; t += 256) {
        int i = t / 80, j = t - i * 80;
        e[i * 85 + j] = (e0[t] + e0[6400 + t]) + (e0[12800 + t] + e0[19200 + t]);
    }
    __syncthreads();

    if (tid < NN) {
        float* er = e + tid * 85;
        float mx = -1e30f;
        for (int j = 0; j < NN; ++j) mx = fmaxf(mx, er[j]);
        float sum = 0.0f;
        for (int j = 0; j < NN; ++j) { float p = expf(er[j] - mx); er[j] = p; sum += p; }
        float inv = 1.0f / sum;
        for (int j = 0; j < NN; ++j) er[j] *= inv;
    }
    __syncthreads();

    int ti = tid >> 4, tj = tid & 15;
    int d0 = tj * 8;
    float o[5][8];
#pragma unroll
    for (int a = 0; a < 5; ++a)
#pragma unroll
        for (int dd = 0; dd < 8; ++dd) o[a][dd] = 0.0f;
    for (int j = 0; j < NN; ++j) {
        float4 x0 = *(const float4*)(Xs + j * 132 + d0);
        float4 x1 = *(const float4*)(Xs + j * 132 + d0 + 4);
        float av[5];
#pragma unroll
        for (int a = 0; a < 5; ++a) av[a] = e[(ti + 16 * a) * 85 + j];
#pragma unroll
        for (int a = 0; a < 5; ++a) {
            o[a][0] += av[a] * x0.x; o[a][1] += av[a] * x0.y;
            o[a][2] += av[a] * x0.z; o[a][3] += av[a] * x0.w;
            o[a][4] += av[a] * x1.x; o[a][5] += av[a] * x1.y;
            o[a][6] += av[a] * x1.z; o[a][7] += av[a] * x1.w;
        }
    }
#pragma unroll
    for (int a = 0; a < 5; ++a) {
        int i = ti + 16 * a;
        if (i < NN) {
            float* dst = XA + (size_t)(b * NN + i) * D1 + d0;
            float4 s0, s1;
            s0.x = o[a][0]; s0.y = o[a][1]; s0.z = o[a][2]; s0.w = o[a][3];
            s1.x = o[a][4]; s1.y = o[a][5]; s1.z = o[a][6]; s1.w = o[a][7];
            *(float4*)(dst) = s0;
            *(float4*)(dst + 4) = s1;
        }
    }
}

// ---------------------------------------------------------------------------
// k_gemm2: h = selu(bn2( xa@Wpa + bpa + x@Wpn + bpn )). (unchanged)
// ---------------------------------------------------------------------------
__global__ __launch_bounds__(256) void k_gemm2(
    const float* __restrict__ XAg, const float* __restrict__ Xg,
    const float* __restrict__ Wpa, const float* __restrict__ Wpn,
    const float* __restrict__ bpa, const float* __restrict__ bpn,
    const float* __restrict__ g2, const float* __restrict__ b2,
    const float* __restrict__ m2, const float* __restrict__ r2,
    float* __restrict__ h)
{
    __shared__ __align__(16) float As[64 * 260];
    __shared__ __align__(16) float Ws[256 * 68];
    int tid = threadIdx.x;
    int row0 = blockIdx.x * 64;
#pragma unroll
    for (int q = 0; q < 16; ++q) {
        int e4 = q * 256 + tid;
        int r = e4 >> 6, k4 = (e4 & 63) * 4;
        float4 v;
        if (k4 < 128) v = *(const float4*)(XAg + (size_t)(row0 + r) * D1 + k4);
        else          v = *(const float4*)(Xg + (size_t)(row0 + r) * D1 + (k4 - 128));
        *(float4*)(As + r * 260 + k4) = v;
    }
#pragma unroll
    for (int q = 0; q < 16; ++q) {
        int e4 = q * 256 + tid;
        int k = e4 >> 4, c4 = (e4 & 15) * 4;
        float4 v;
        if (k < 128) v = *(const float4*)(Wpa + k * D2 + c4);
        else         v = *(const float4*)(Wpn + (k - 128) * D2 + c4);
        *(float4*)(Ws + k * 68 + c4) = v;
    }
    __syncthreads();
    int rl = tid >> 2, cq = (tid & 3) * 16;
    float acc[16];
#pragma unroll
    for (int m = 0; m < 16; ++m) acc[m] = 0.0f;
    for (int k = 0; k < 256; ++k) {
        float a = As[rl * 260 + k];
        float4 w0 = *(const float4*)(Ws + k * 68 + cq);
        float4 w1 = *(const float4*)(Ws + k * 68 + cq + 4);
        float4 w2 = *(const float4*)(Ws + k * 68 + cq + 8);
        float4 w3 = *(const float4*)(Ws + k * 68 + cq + 12);
        acc[0] += a * w0.x;  acc[1] += a * w0.y;  acc[2] += a * w0.z;  acc[3] += a * w0.w;
        acc[4] += a * w1.x;  acc[5] += a * w1.y;  acc[6] += a * w1.z;  acc[7] += a * w1.w;
        acc[8] += a * w2.x;  acc[9] += a * w2.y;  acc[10] += a * w2.z; acc[11] += a * w2.w;
        acc[12] += a * w3.x; acc[13] += a * w3.y; acc[14] += a * w3.z; acc[15] += a * w3.w;
    }
#pragma unroll
    for (int m = 0; m < 16; ++m) {
        int c = cq + m;
        float t = acc[m] + bpa[c] + bpn[c];
        t = (t - m2[c]) * r2[c] * g2[c] + b2[c];
        h[(size_t)(row0 + rl) * D2 + c] = selu_f(t);
    }
}

// ---------------------------------------------------------------------------
// k_head (R6): one wave per batch. h staged in LDS (stride 65 -> 2-way
// banks). scores -> sigmoid -> rank-by-count top-53 (ties by index =
// jax.lax.top_k) -> proj -> W_node -> out (256x2 fp32)
// ---------------------------------------------------------------------------
__global__ __launch_bounds__(64) void k_head(
    const float* __restrict__ h, const float* __restrict__ Wpool,
    const float* __restrict__ bpool, const float* __restrict__ Wproj,
    const float* __restrict__ bproj, const float* __restrict__ Wnode,
    const float* __restrict__ bnode, float* __restrict__ out)
{
    __shared__ float hs[NN * 65];                 // 17.4 KB
    __shared__ float sc[NN], pv[NN], sel[NP];
    int lane = threadIdx.x, b = blockIdx.x;
    const float* hb = h + (size_t)(b * NN) * D2;
    for (int t = lane; t < NN * 16; t += 64) {    // 67 rows x 16 float4s
        int j = t >> 4, c4 = (t & 15) * 4;
        float4 v = *(const float4*)(hb + (size_t)j * D2 + c4);
        float* dst = hs + j * 65 + c4;
        dst[0] = v.x; dst[1] = v.y; dst[2] = v.z; dst[3] = v.w;
    }
    __syncthreads();
    for (int j = lane; j < NN; j += 64) {
        const float* hr = hs + j * 65;
        float z = 0.0f;
        for (int c = 0; c < D2; ++c) z += hr[c] * Wpool[c];
        z += bpool[0];
        float s = 1.0f / (1.0f + expf(-z));
        float q = 0.0f;
        for (int c = 0; c < D2; ++c) q += (hr[c] * s) * Wproj[c];
        q += bproj[0];
        sc[j] = s; pv[j] = q;
    }
    __syncthreads();
    for (int j = lane; j < NN; j += 64) {
        float sj = sc[j]; int rank = 0;
        for (int k = 0; k < NN; ++k) {
            float sk = sc[k];
            rank += (sk > sj) || (sk == sj && k < j);
        }
        if (rank < NP) sel[rank] = pv[j];
    }
    __syncthreads();
    if (lane < 2) {
        float o = 0.0f;
        for (int r = 0; r < NP; ++r) o += sel[r] * Wnode[r * 2 + lane];
        out[b * 2 + lane] = o + bnode[lane];
    }
}

// ---------------------------------------------------------------------------
extern "C" void kernel_launch(void* const* d_in, const int* in_sizes, int n_in,
                              void* d_out, int out_size, void* d_ws, size_t ws_size,
                              hipStream_t stream)
{
    const float* feat  = (const float*)d_in[0];
    const float* Wll   = (const float*)d_in[1];
    const float* bll   = (const float*)d_in[2];
    const float* g1    = (const float*)d_in[3];
    const float* b1    = (const float*)d_in[4];
    const float* m1    = (const float*)d_in[5];
    const float* v1    = (const float*)d_in[6];
    const float* Wap   = (const float*)d_in[7];
    const float* bap   = (const float*)d_in[8];
    const float* attw  = (const float*)d_in[9];
    const float* Wpa   = (const float*)d_in[10];
    const float* bpa   = (const float*)d_in[11];
    const float* Wpn   = (const float*)d_in[12];
    const float* bpn   = (const float*)d_in[13];
    const float* g2    = (const float*)d_in[14];
    const float* b2    = (const float*)d_in[15];
    const float* m2    = (const float*)d_in[16];
    const float* v2    = (const float*)d_in[17];
    const float* Wpool = (const float*)d_in[18];
    const float* bpool = (const float*)d_in[19];
    const float* Wproj = (const float*)d_in[20];
    const float* bproj = (const float*)d_in[21];
    const float* Wnode = (const float*)d_in[22];
    const float* bnode = (const float*)d_in[23];
    float* out = (float*)d_out;

    const size_t ybytes = (size_t)ROWS1 * D1 * 4;            // 26,345,472
    const size_t xbytes = (size_t)ROWS2 * D1 * 4;            // 8,781,824
    const size_t hbytes = (size_t)ROWS2 * D2 * 4;            // 4,390,912
    const size_t wbytes = (size_t)128 * 1024 * 4 + 64 * 128 * 4 + 4096;
    size_t need2 = 2 * ybytes + 2 * xbytes + hbytes + wbytes;
    int nsplit = (ws_size >= need2) ? 2 : 1;

    char* w = (char*)d_ws;
    float* y0 = (float*)w; w += ybytes;
    float* y1 = y0;
    if (nsplit == 2) { y1 = (float*)w; w += ybytes; }
    float* X    = (float*)w; w += xbytes;
    float* XA   = (float*)w; w += xbytes;
    float* hbuf = (float*)w; w += hbytes;
    float* WllT = (float*)w; w += (size_t)128 * 1024 * 4;
    float* WapT = (float*)w; w += (size_t)64 * 128 * 4;
    float* r1   = (float*)w; w += 128 * 4;
    float* r2   = (float*)w; w += 64 * 4;
    float* epart = y0;   // 1024*6400*4 = 26,214,400 <= ybytes (y dead after k_pool)

    hipLaunchKernelGGL(k_pre,   dim3(545),  dim3(256), 0, stream,
                       Wll, Wap, v1, v2, WllT, WapT, r1, r2);
    hipLaunchKernelGGL(k_gemm1, dim3(nsplit == 2 ? 804 : 402), dim3(256), 0, stream,
                       feat, WllT, y0, y1, nsplit);
    hipLaunchKernelGGL(k_pool,  dim3(8576), dim3(256), 0, stream,
                       y0, y1, nsplit - 1, bll, g1, b1, m1, r1, X);
    hipLaunchKernelGGL(k_attn1, dim3(1024), dim3(256), 0, stream,
                       X, WapT, bap, attw, epart);
    hipLaunchKernelGGL(k_attn2, dim3(256),  dim3(256), 0, stream,
                       X, epart, XA);
    hipLaunchKernelGGL(k_gemm2, dim3(268),  dim3(256), 0, stream,
                       XA, X, Wpa, Wpn, bpa, bpn, g2, b2, m2, r2, hbuf);
    hipLaunchKernelGGL(k_head,  dim3(256),  dim3(64),  0, stream,
                       hbuf, Wpool, bpool, Wproj, bproj, Wnode, bnode, out);
}